// Round 14
// baseline (221.783 us; speedup 1.0000x reference)
//
#include <hip/hip_runtime.h>

// R14: k_final v5 — persistent 256-n blocks (grid 1024), ping-pong LDS pipeline:
// slot(t) = {xr(t-1) issue; A(t) convert+write; xv(t+1) prefetch; D(t-1)
// readback+store} | bar | B(t) | bar | C(t) | bar. wq/bm amortized 4x.
// All index formulas verbatim from R13 (verified). k_stats/k_main/k_comb = R13.

#define B_ 16
#define C_ 128
#define N_ 16384

typedef short bf16x8 __attribute__((ext_vector_type(8)));
typedef float f32x4 __attribute__((ext_vector_type(4)));
typedef unsigned u32x2 __attribute__((ext_vector_type(2)));

__device__ __forceinline__ ushort f2bf(float f) {
    union { float f; unsigned u; } v; v.f = f;
    unsigned r = (v.u + 0x7FFFu + ((v.u >> 16) & 1u)) >> 16;
    return (ushort)r;
}
__device__ __forceinline__ float bf2f(unsigned h) {
    union { unsigned u; float f; } v; v.u = h << 16;
    return v.f;
}
__device__ __forceinline__ float fc4(const float4& v, int j) {
    return j == 0 ? v.x : (j == 1 ? v.y : (j == 2 ? v.z : v.w));
}

// ---------------- K1: GroupNorm stats -> sc/bi ; blocks >=512 pack qkv_w ----
__global__ void k_stats(const float* __restrict__ x, const float* __restrict__ gnw,
                        const float* __restrict__ gnb, float* __restrict__ sc,
                        float* __restrict__ bi,
                        const float* __restrict__ qkvw, ushort* __restrict__ wbf) {
    int bg = blockIdx.x;
    if (bg >= 512) {
        int i = (bg - 512) * 1024 + threadIdx.x;
        if (i < 384 * 128) wbf[i] = f2bf(qkvw[i]);
        return;
    }
    const float4* p = (const float4*)(x + (size_t)bg * (4 * N_));
    float s = 0.f, s2 = 0.f;
    for (int i = threadIdx.x; i < N_; i += 1024) {
        float4 v = p[i];
        s  += v.x + v.y + v.z + v.w;
        s2 += v.x * v.x + v.y * v.y + v.z * v.z + v.w * v.w;
    }
    #pragma unroll
    for (int d = 32; d > 0; d >>= 1) { s += __shfl_xor(s, d); s2 += __shfl_xor(s2, d); }
    __shared__ float ls[16], ls2[16];
    int wid = threadIdx.x >> 6, lane = threadIdx.x & 63;
    if (lane == 0) { ls[wid] = s; ls2[wid] = s2; }
    __syncthreads();
    if (threadIdx.x == 0) {
        float S = 0.f, S2 = 0.f;
        #pragma unroll
        for (int i = 0; i < 16; ++i) { S += ls[i]; S2 += ls2[i]; }
        float m = S / 65536.f;
        float var = S2 / 65536.f - m * m;
        float rs = rsqrtf(var + 1e-5f);
        int b = bg >> 5, g = bg & 31;
        #pragma unroll
        for (int i = 0; i < 4; ++i) {
            int c = g * 4 + i;
            float scv = rs * gnw[c];
            sc[b * 128 + c] = scv;
            bi[b * 128 + c] = gnb[c] - m * scv;
        }
    }
}

// ---------------- K2: normalize+transpose+qkv+qsum+ksm+v+MFMA-ctx ----------
#define MFMA16(A, Bv, Cc) __builtin_amdgcn_mfma_f32_16x16x32_bf16(A, Bv, Cc, 0, 0, 0)

#define DO_Q(J) do { \
    f32x4 acc = {0.f, 0.f, 0.f, 0.f}; \
    acc = MFMA16(wf[J][0], xb[0], acc); acc = MFMA16(wf[J][1], xb[1], acc); \
    acc = MFMA16(wf[J][2], xb[2], acc); acc = MFMA16(wf[J][3], xb[3], acc); \
    qacc[J][0] += __expf(acc[0]); qacc[J][1] += __expf(acc[1]); \
    qacc[J][2] += __expf(acc[2]); qacc[J][3] += __expf(acc[3]); \
} while (0)

#define DO_K(JLO, H) do { \
    f32x4 aL = {0.f, 0.f, 0.f, 0.f}, aH = {0.f, 0.f, 0.f, 0.f}; \
    aL = MFMA16(wf[JLO][0], xb[0], aL);     aH = MFMA16(wf[(JLO)+1][0], xb[0], aH); \
    aL = MFMA16(wf[JLO][1], xb[1], aL);     aH = MFMA16(wf[(JLO)+1][1], xb[1], aH); \
    aL = MFMA16(wf[JLO][2], xb[2], aL);     aH = MFMA16(wf[(JLO)+1][2], xb[2], aH); \
    aL = MFMA16(wf[JLO][3], xb[3], aL);     aH = MFMA16(wf[(JLO)+1][3], xb[3], aH); \
    float eL0 = __expf(aL[0]), eL1 = __expf(aL[1]), eL2 = __expf(aL[2]), eL3 = __expf(aL[3]); \
    float eH0 = __expf(aH[0]), eH1 = __expf(aH[1]), eH2 = __expf(aH[2]), eH3 = __expf(aH[3]); \
    float s = eL0 + eL1 + eL2 + eL3 + eH0 + eH1 + eH2 + eH3; \
    s += __shfl_xor(s, 16); s += __shfl_xor(s, 32); \
    float rinv = 1.f / s; \
    ksm[H][lg * 4 + 0][nloc] = f2bf(eL0 * rinv); \
    ksm[H][lg * 4 + 1][nloc] = f2bf(eL1 * rinv); \
    ksm[H][lg * 4 + 2][nloc] = f2bf(eL2 * rinv); \
    ksm[H][lg * 4 + 3][nloc] = f2bf(eL3 * rinv); \
    ksm[H][16 + lg * 4 + 0][nloc] = f2bf(eH0 * rinv); \
    ksm[H][16 + lg * 4 + 1][nloc] = f2bf(eH1 * rinv); \
    ksm[H][16 + lg * 4 + 2][nloc] = f2bf(eH2 * rinv); \
    ksm[H][16 + lg * 4 + 3][nloc] = f2bf(eH3 * rinv); \
} while (0)

#define DO_V(J, HV, EB) do { \
    f32x4 acc = {0.f, 0.f, 0.f, 0.f}; \
    acc = MFMA16(wf[J][0], xb[0], acc); acc = MFMA16(wf[J][1], xb[1], acc); \
    acc = MFMA16(wf[J][2], xb[2], acc); acc = MFMA16(wf[J][3], xb[3], acc); \
    vls[HV][(EB) + lg * 4 + 0][nloc] = f2bf(acc[0]); \
    vls[HV][(EB) + lg * 4 + 1][nloc] = f2bf(acc[1]); \
    vls[HV][(EB) + lg * 4 + 2][nloc] = f2bf(acc[2]); \
    vls[HV][(EB) + lg * 4 + 3][nloc] = f2bf(acc[3]); \
} while (0)

#define DO_CTX() do { \
    bf16x8 A0 = *(const bf16x8*)&ksm[wid][l15][lg * 8]; \
    bf16x8 A1 = *(const bf16x8*)&ksm[wid][16 + l15][lg * 8]; \
    bf16x8 B0 = *(const bf16x8*)&vls[wid][l15][lg * 8]; \
    bf16x8 B1 = *(const bf16x8*)&vls[wid][16 + l15][lg * 8]; \
    cacc[0][0] = MFMA16(A0, B0, cacc[0][0]); \
    cacc[0][1] = MFMA16(A0, B1, cacc[0][1]); \
    cacc[1][0] = MFMA16(A1, B0, cacc[1][0]); \
    cacc[1][1] = MFMA16(A1, B1, cacc[1][1]); \
} while (0)

__global__ __launch_bounds__(256, 2) void k_main(
    const float* __restrict__ x, const ushort* __restrict__ wbf,
    const float* __restrict__ scA, const float* __restrict__ biA,
    float* __restrict__ qsumP, float* __restrict__ ctxP) {
    int blk = blockIdx.x;
    int b = blk >> 6, nb = blk & 63;
    int tid = threadIdx.x, wid = tid >> 6, lane = tid & 63;
    int l15 = lane & 15, lg = lane >> 4;

    __shared__ __align__(16) ushort xs[4096];
    __shared__ __align__(16) ushort ksm[4][32][40];
    __shared__ __align__(16) ushort vls[4][32][40];

    bf16x8 wf[6][4];
    {
        const ushort* wr = wbf + (size_t)(wid * 96 + l15) * 128 + lg * 8;
        #pragma unroll
        for (int j = 0; j < 6; ++j)
            #pragma unroll
            for (int kc = 0; kc < 4; ++kc)
                wf[j][kc] = *(const bf16x8*)(wr + j * 2048 + kc * 32);
    }

    float qacc[6][4];
    #pragma unroll
    for (int j = 0; j < 6; ++j)
        #pragma unroll
        for (int r = 0; r < 4; ++r) qacc[j][r] = 0.f;
    f32x4 cacc[2][2];
    #pragma unroll
    for (int di = 0; di < 2; ++di)
        #pragma unroll
        for (int ei = 0; ei < 2; ++ei) cacc[di][ei] = (f32x4){0.f, 0.f, 0.f, 0.f};

    const int pk_ = tid & 7, pcb = tid >> 3;
    const float* xrow = x + (size_t)b * (C_ * N_) + nb * 256 + pk_ * 4;
    float scv[4], biv[4];
    #pragma unroll
    for (int i = 0; i < 4; ++i) {
        scv[i] = scA[b * 128 + pcb * 4 + i];
        biv[i] = biA[b * 128 + pcb * 4 + i];
    }
    unsigned boffj[4];
    #pragma unroll
    for (int j = 0; j < 4; ++j) {
        int n = pk_ * 4 + j;
        boffj[j] = (unsigned)(n * 256 + (((pcb >> 1) * 16) ^ ((n & 7) << 4)) + (pcb & 1) * 8);
    }

    float4 vbuf[4];
    #pragma unroll
    for (int i = 0; i < 4; ++i)
        vbuf[i] = *(const float4*)(xrow + (size_t)(pcb * 4 + i) * N_);

    for (int ch = 0; ch < 8; ++ch) {
        __syncthreads();
        unsigned e[4][4];
        #pragma unroll
        for (int i = 0; i < 4; ++i) {
            float s = scv[i], t = biv[i];
            e[i][0] = f2bf(vbuf[i].x * s + t);
            e[i][1] = f2bf(vbuf[i].y * s + t);
            e[i][2] = f2bf(vbuf[i].z * s + t);
            e[i][3] = f2bf(vbuf[i].w * s + t);
        }
        if (ch < 7) {
            #pragma unroll
            for (int i = 0; i < 4; ++i)
                vbuf[i] = *(const float4*)(xrow + (size_t)(pcb * 4 + i) * N_ + (ch + 1) * 32);
        }
        #pragma unroll
        for (int j = 0; j < 4; ++j) {
            u32x2 wj;
            wj.x = e[0][j] | (e[1][j] << 16);
            wj.y = e[2][j] | (e[3][j] << 16);
            *(u32x2*)((char*)xs + boffj[j]) = wj;
        }
        if (ch > 0) DO_CTX();
        __syncthreads();

        #pragma unroll
        for (int nt = 0; nt < 2; ++nt) {
            int row = nt * 16 + l15;
            bf16x8 xb[4];
            #pragma unroll
            for (int kc = 0; kc < 4; ++kc) {
                unsigned off = (unsigned)(row * 256 +
                    (((kc * 4 + lg) * 16) ^ ((row & 7) << 4)));
                xb[kc] = *(const bf16x8*)((const char*)xs + off);
            }
            int nloc = nt * 16 + l15;

            if (wid == 0) {
                DO_Q(0); DO_Q(1); DO_Q(2); DO_Q(3); DO_Q(4); DO_Q(5);
            } else if (wid == 1) {
                DO_Q(0); DO_Q(1); DO_K(2, 0); DO_K(4, 1);
            } else if (wid == 2) {
                DO_K(0, 2); DO_K(2, 3); DO_V(4, 0, 0); DO_V(5, 0, 16);
            } else {
                DO_V(0, 1, 0); DO_V(1, 1, 16); DO_V(2, 2, 0);
                DO_V(3, 2, 16); DO_V(4, 3, 0); DO_V(5, 3, 16);
            }
        }
    }
    __syncthreads();
    DO_CTX();

    int nq = (wid == 0) ? 6 : (wid == 1 ? 2 : 0);
    #pragma unroll
    for (int j = 0; j < 6; ++j) {
        if (j < nq) {
            #pragma unroll
            for (int r = 0; r < 4; ++r) {
                float s = qacc[j][r];
                s += __shfl_xor(s, 1); s += __shfl_xor(s, 2);
                s += __shfl_xor(s, 4); s += __shfl_xor(s, 8);
                if (l15 == 0)
                    qsumP[(size_t)blk * 128 + (wid * 6 + j) * 16 + lg * 4 + r] = s;
            }
        }
    }
    float* cp = ctxP + (size_t)blk * 4096 + wid * 1024;
    #pragma unroll
    for (int di = 0; di < 2; ++di)
        #pragma unroll
        for (int ei = 0; ei < 2; ++ei)
            #pragma unroll
            for (int r = 0; r < 4; ++r)
                cp[(di * 16 + lg * 4 + r) * 32 + ei * 16 + l15] = cacc[di][ei][r];
}

// ---------------- K3: reduce ctxP + qsum, build M''[b][c][hd] bf16 ----------------
__global__ __launch_bounds__(1024) void k_comb(
    const float* __restrict__ ctxP, const float* __restrict__ qsumP,
    const float* __restrict__ projw, ushort* __restrict__ mpp) {
    int b = blockIdx.x, tid = threadIdx.x;
    __shared__ float ctx[4096];
    __shared__ float qinv[128];
    const float* base = ctxP + (size_t)b * 64 * 4096;
    #pragma unroll
    for (int r = 0; r < 4; ++r) {
        int i = r * 1024 + tid;
        float s = 0.f;
        for (int q = 0; q < 64; ++q) s += base[(size_t)q * 4096 + i];
        ctx[i] = s;
    }
    if (tid < 128) {
        float s = 0.f;
        const float* p = qsumP + (size_t)b * 64 * 128 + tid;
        for (int q = 0; q < 64; ++q) s += p[q * 128];
        qinv[tid] = 1.f / s;
    }
    __syncthreads();
    if (tid < 256) {
        int c = tid >> 1, hd0 = (tid & 1) * 64;
        unsigned ow[32];
        for (int k = 0; k < 64; ++k) {
            int hd = hd0 + k, h = hd >> 5, d = hd & 31;
            const float* pw = projw + c * 128 + h * 32;
            const float* cx = ctx + h * 1024 + d * 32;
            float s = 0.f;
            #pragma unroll 8
            for (int e = 0; e < 32; ++e) s += pw[e] * cx[e];
            s *= qinv[hd];
            ushort bv = f2bf(s);
            if (k & 1) ow[k >> 1] |= ((unsigned)bv) << 16; else ow[k >> 1] = bv;
        }
        ushort* dst = mpp + ((size_t)(b * 128 + c)) * 128 + hd0;
        #pragma unroll
        for (int q = 0; q < 8; ++q) {
            uint4 t; t.x = ow[q * 4]; t.y = ow[q * 4 + 1];
            t.z = ow[q * 4 + 2]; t.w = ow[q * 4 + 3];
            ((uint4*)dst)[q] = t;
        }
    }
}

// ---------------- K4 v5: persistent 256-n blocks, ping-pong pipeline ----------------
__global__ __launch_bounds__(256) void k_final(
    const ushort* __restrict__ wbf, const ushort* __restrict__ mpp,
    const float* __restrict__ scA, const float* __restrict__ biA,
    const float* __restrict__ projb, const float* __restrict__ x,
    float* __restrict__ out) {
    int blk = blockIdx.x;
    int b = blk >> 6, nb = blk & 63;
    int tid = threadIdx.x, wid = tid >> 6, lane = tid & 63;
    int l15 = lane & 15, lg = lane >> 4;

    __shared__ __align__(16) char lds[32768];  // two 16-KB ping-pong buffers

    bf16x8 wq[2][4];
    #pragma unroll
    for (int j = 0; j < 2; ++j) {
        const ushort* wr = wbf + (size_t)((wid * 2 + j) * 16 + l15) * 128 + lg * 8;
        #pragma unroll
        for (int kc = 0; kc < 4; ++kc) wq[j][kc] = *(const bf16x8*)(wr + kc * 32);
    }
    bf16x8 bm[2][4];
    #pragma unroll
    for (int ctk = 0; ctk < 2; ++ctk) {
        const ushort* br = mpp + ((size_t)(b * 128 + (wid * 2 + ctk) * 16 + l15)) * 128 + lg * 8;
        #pragma unroll
        for (int kc = 0; kc < 4; ++kc) bm[ctk][kc] = *(const bf16x8*)(br + kc * 32);
    }

    const int pk_ = tid & 15, pcb = tid >> 4;
    const float* xrow = x + (size_t)b * (C_ * N_) + nb * 256 + pk_ * 4;
    float scv[8], biv[8];
    #pragma unroll
    for (int i = 0; i < 8; ++i) {
        int c = pcb * 8 + i;
        scv[i] = scA[b * 128 + c];
        biv[i] = biA[b * 128 + c];
    }

    // prefetch tile 0
    float4 xv[8];
    #pragma unroll
    for (int i = 0; i < 8; ++i)
        xv[i] = *(const float4*)(xrow + (size_t)(pcb * 8 + i) * N_);

    for (int t = 0; t < 4; ++t) {
        char* bufX = lds + (t & 1) * 16384;        // xs(t), then att(t)
        char* bufE = lds + ((t + 1) & 1) * 16384;  // eqls(t)

        // ---- D(t-1) step 1: issue residual re-reads (L2-hot)
        f32x4 xr[8];
        if (t > 0) {
            const float* rrow = xrow + (t - 1) * 64;
            #pragma unroll
            for (int i = 0; i < 8; ++i)
                xr[i] = *(const f32x4*)(rrow + (size_t)(pcb * 8 + i) * N_);
        }

        // ---- A(t): convert xv -> xs(bufX)
        #pragma unroll
        for (int j = 0; j < 4; ++j) {
            int n = pk_ * 4 + j;
            uint4 wj;
            wj.x = (unsigned)f2bf(fc4(xv[0], j) * scv[0] + biv[0]) |
                   ((unsigned)f2bf(fc4(xv[1], j) * scv[1] + biv[1]) << 16);
            wj.y = (unsigned)f2bf(fc4(xv[2], j) * scv[2] + biv[2]) |
                   ((unsigned)f2bf(fc4(xv[3], j) * scv[3] + biv[3]) << 16);
            wj.z = (unsigned)f2bf(fc4(xv[4], j) * scv[4] + biv[4]) |
                   ((unsigned)f2bf(fc4(xv[5], j) * scv[5] + biv[5]) << 16);
            wj.w = (unsigned)f2bf(fc4(xv[6], j) * scv[6] + biv[6]) |
                   ((unsigned)f2bf(fc4(xv[7], j) * scv[7] + biv[7]) << 16);
            unsigned byte = (unsigned)(n * 256 + ((pcb * 16) ^ ((n & 7) << 4)));
            *(uint4*)(bufX + byte) = wj;
        }
        // prefetch tile t+1 (in flight through B/C)
        if (t < 3) {
            const float* prow = xrow + (t + 1) * 64;
            #pragma unroll
            for (int i = 0; i < 8; ++i)
                xv[i] = *(const float4*)(prow + (size_t)(pcb * 8 + i) * N_);
        }
        // ---- D(t-1) step 2: att readback + combine + store (overlaps A's writes)
        if (t > 0) {
            char* bufD = lds + ((t - 1) & 1) * 16384;
            size_t obase = (size_t)b * (C_ * N_) + nb * 256 + (t - 1) * 64 + pk_ * 4;
            #pragma unroll
            for (int i = 0; i < 8; ++i) {
                int c = pcb * 8 + i;
                unsigned byte = (unsigned)(c * 128 +
                    (((pk_ >> 1) * 16) ^ ((c & 7) << 4)) + (pk_ & 1) * 8);
                u32x2 pk = *(const u32x2*)(bufD + byte);
                float pbv = projb[c];
                f32x4 o4;
                o4[0] = bf2f(pk.x & 0xffffu) + pbv + xr[i][0];
                o4[1] = bf2f(pk.x >> 16)     + pbv + xr[i][1];
                o4[2] = bf2f(pk.y & 0xffffu) + pbv + xr[i][2];
                o4[3] = bf2f(pk.y >> 16)     + pbv + xr[i][3];
                *(f32x4*)(out + obase + (size_t)c * N_) = o4;
            }
        }
        __syncthreads();

        // ---- B(t): xs -> q-MFMA + exp -> eqls(bufE)
        #pragma unroll
        for (int nt = 0; nt < 4; ++nt) {
            int row = nt * 16 + l15;
            bf16x8 xb[4];
            #pragma unroll
            for (int kc = 0; kc < 4; ++kc) {
                unsigned off = (unsigned)(row * 256 + (((kc * 4 + lg) * 16) ^ ((row & 7) << 4)));
                xb[kc] = *(const bf16x8*)(bufX + off);
            }
            #pragma unroll
            for (int j = 0; j < 2; ++j) {
                f32x4 a = {0.f, 0.f, 0.f, 0.f};
                #pragma unroll
                for (int kc = 0; kc < 4; ++kc) a = MFMA16(wq[j][kc], xb[kc], a);
                u32x2 pk;
                pk.x = (unsigned)f2bf(__expf(a[0])) | ((unsigned)f2bf(__expf(a[1])) << 16);
                pk.y = (unsigned)f2bf(__expf(a[2])) | ((unsigned)f2bf(__expf(a[3])) << 16);
                int ot = wid * 2 + j;
                unsigned byte = (unsigned)(row * 256 +
                    (((ot * 2 + (lg >> 1)) * 16) ^ ((row & 7) << 4)) + (lg & 1) * 8);
                *(u32x2*)(bufE + byte) = pk;
            }
        }
        __syncthreads();

        // ---- C(t): eqls -> out-MFMA -> att(bufX)
        #pragma unroll
        for (int nt = 0; nt < 4; ++nt) {
            int row = nt * 16 + l15;
            bf16x8 af[4];
            #pragma unroll
            for (int kc = 0; kc < 4; ++kc) {
                unsigned off = (unsigned)(row * 256 + (((kc * 4 + lg) * 16) ^ ((row & 7) << 4)));
                af[kc] = *(const bf16x8*)(bufE + off);
            }
            #pragma unroll
            for (int ctk = 0; ctk < 2; ++ctk) {
                f32x4 a = {0.f, 0.f, 0.f, 0.f};
                #pragma unroll
                for (int kc = 0; kc < 4; ++kc) a = MFMA16(af[kc], bm[ctk][kc], a);
                int c = (wid * 2 + ctk) * 16 + l15;
                u32x2 pk;
                pk.x = (unsigned)f2bf(a[0]) | ((unsigned)f2bf(a[1]) << 16);
                pk.y = (unsigned)f2bf(a[2]) | ((unsigned)f2bf(a[3]) << 16);
                unsigned byte = (unsigned)(c * 128 +
                    (((nt * 2 + (lg >> 1)) * 16) ^ ((c & 7) << 4)) + (lg & 1) * 8);
                *(u32x2*)(bufX + byte) = pk;
            }
        }
        __syncthreads();
    }

    // ---- epilogue D(3)
    {
        char* bufD = lds + 16384;  // (3&1)*16384
        const float* rrow = xrow + 3 * 64;
        f32x4 xr[8];
        #pragma unroll
        for (int i = 0; i < 8; ++i)
            xr[i] = *(const f32x4*)(rrow + (size_t)(pcb * 8 + i) * N_);
        size_t obase = (size_t)b * (C_ * N_) + nb * 256 + 3 * 64 + pk_ * 4;
        #pragma unroll
        for (int i = 0; i < 8; ++i) {
            int c = pcb * 8 + i;
            unsigned byte = (unsigned)(c * 128 +
                (((pk_ >> 1) * 16) ^ ((c & 7) << 4)) + (pk_ & 1) * 8);
            u32x2 pk = *(const u32x2*)(bufD + byte);
            float pbv = projb[c];
            f32x4 o4;
            o4[0] = bf2f(pk.x & 0xffffu) + pbv + xr[i][0];
            o4[1] = bf2f(pk.x >> 16)     + pbv + xr[i][1];
            o4[2] = bf2f(pk.y & 0xffffu) + pbv + xr[i][2];
            o4[3] = bf2f(pk.y >> 16)     + pbv + xr[i][3];
            *(f32x4*)(out + obase + (size_t)c * N_) = o4;
        }
    }
}

extern "C" void kernel_launch(void* const* d_in, const int* in_sizes, int n_in,
                              void* d_out, int out_size, void* d_ws, size_t ws_size,
                              hipStream_t stream) {
    const float* x     = (const float*)d_in[0];
    const float* gnw   = (const float*)d_in[1];
    const float* gnb   = (const float*)d_in[2];
    const float* qkvw  = (const float*)d_in[3];
    const float* projw = (const float*)d_in[4];
    const float* projb = (const float*)d_in[5];
    float* out = (float*)d_out;

    char* ws = (char*)d_ws;
    ushort* wbf   = (ushort*)(ws);                // 98,304 B
    float*  qsumP = (float*)(ws + 102400);        // 524,288 B
    ushort* mpp   = (ushort*)(ws + 626688);       // 524,288 B
    float*  sc    = (float*)(ws + 1150976);       // 8,192 B
    float*  bi    = (float*)(ws + 1159168);       // 8,192 B
    float*  ctxP  = (float*)(ws + 1167360);       // 16,777,216 B (end: 17,944,576)

    k_stats<<<560,  1024, 0, stream>>>(x, gnw, gnb, sc, bi, qkvw, wbf);
    k_main <<<1024, 256,  0, stream>>>(x, wbf, sc, bi, qsumP, ctxP);
    k_comb <<<16,   1024, 0, stream>>>(ctxP, qsumP, projw, mpp);
    k_final<<<1024, 256,  0, stream>>>(wbf, mpp, sc, bi, projb, x, out);
}

// Round 15
// 203.808 us; speedup vs baseline: 1.0882x; 1.0882x over previous
//
#include <hip/hip_runtime.h>

// R15: R12 (best, 211.5us) + ONE change: k_final att LDS row stride 128->136B
// (kills the 4-way bank-conflict overlay: every 128B row started at bank 0 and
// D-phase's 4 rows per instr had c==i mod 8 -> identical XOR -> full overlay).
// eqls moves to offset 17408; LDS 33792. All else byte-identical to R12.

#define B_ 16
#define C_ 128
#define N_ 16384

typedef short bf16x8 __attribute__((ext_vector_type(8)));
typedef float f32x4 __attribute__((ext_vector_type(4)));
typedef unsigned u32x2 __attribute__((ext_vector_type(2)));

__device__ __forceinline__ ushort f2bf(float f) {
    union { float f; unsigned u; } v; v.f = f;
    unsigned r = (v.u + 0x7FFFu + ((v.u >> 16) & 1u)) >> 16;
    return (ushort)r;
}
__device__ __forceinline__ float bf2f(unsigned h) {
    union { unsigned u; float f; } v; v.u = h << 16;
    return v.f;
}

// ---------------- K1: GroupNorm stats -> sc/bi ; blocks >=512 pack qkv_w ----
__global__ void k_stats(const float* __restrict__ x, const float* __restrict__ gnw,
                        const float* __restrict__ gnb, float* __restrict__ sc,
                        float* __restrict__ bi,
                        const float* __restrict__ qkvw, ushort* __restrict__ wbf) {
    int bg = blockIdx.x;
    if (bg >= 512) {
        int i = (bg - 512) * 1024 + threadIdx.x;
        if (i < 384 * 128) wbf[i] = f2bf(qkvw[i]);
        return;
    }
    const float4* p = (const float4*)(x + (size_t)bg * (4 * N_));
    float s = 0.f, s2 = 0.f;
    for (int i = threadIdx.x; i < N_; i += 1024) {
        float4 v = p[i];
        s  += v.x + v.y + v.z + v.w;
        s2 += v.x * v.x + v.y * v.y + v.z * v.z + v.w * v.w;
    }
    #pragma unroll
    for (int d = 32; d > 0; d >>= 1) { s += __shfl_xor(s, d); s2 += __shfl_xor(s2, d); }
    __shared__ float ls[16], ls2[16];
    int wid = threadIdx.x >> 6, lane = threadIdx.x & 63;
    if (lane == 0) { ls[wid] = s; ls2[wid] = s2; }
    __syncthreads();
    if (threadIdx.x == 0) {
        float S = 0.f, S2 = 0.f;
        #pragma unroll
        for (int i = 0; i < 16; ++i) { S += ls[i]; S2 += ls2[i]; }
        float m = S / 65536.f;
        float var = S2 / 65536.f - m * m;
        float rs = rsqrtf(var + 1e-5f);
        int b = bg >> 5, g = bg & 31;
        #pragma unroll
        for (int i = 0; i < 4; ++i) {
            int c = g * 4 + i;
            float scv = rs * gnw[c];
            sc[b * 128 + c] = scv;
            bi[b * 128 + c] = gnb[c] - m * scv;
        }
    }
}

// ---------------- K2: normalize+transpose+qkv+qsum+ksm+v+MFMA-ctx (no eqT) --------
#define MFMA16(A, Bv, Cc) __builtin_amdgcn_mfma_f32_16x16x32_bf16(A, Bv, Cc, 0, 0, 0)

#define DO_Q(J) do { \
    f32x4 acc = {0.f, 0.f, 0.f, 0.f}; \
    acc = MFMA16(wf[J][0], xb[0], acc); acc = MFMA16(wf[J][1], xb[1], acc); \
    acc = MFMA16(wf[J][2], xb[2], acc); acc = MFMA16(wf[J][3], xb[3], acc); \
    qacc[J][0] += __expf(acc[0]); qacc[J][1] += __expf(acc[1]); \
    qacc[J][2] += __expf(acc[2]); qacc[J][3] += __expf(acc[3]); \
} while (0)

#define DO_K(JLO, H) do { \
    f32x4 aL = {0.f, 0.f, 0.f, 0.f}, aH = {0.f, 0.f, 0.f, 0.f}; \
    aL = MFMA16(wf[JLO][0], xb[0], aL);     aH = MFMA16(wf[(JLO)+1][0], xb[0], aH); \
    aL = MFMA16(wf[JLO][1], xb[1], aL);     aH = MFMA16(wf[(JLO)+1][1], xb[1], aH); \
    aL = MFMA16(wf[JLO][2], xb[2], aL);     aH = MFMA16(wf[(JLO)+1][2], xb[2], aH); \
    aL = MFMA16(wf[JLO][3], xb[3], aL);     aH = MFMA16(wf[(JLO)+1][3], xb[3], aH); \
    float eL0 = __expf(aL[0]), eL1 = __expf(aL[1]), eL2 = __expf(aL[2]), eL3 = __expf(aL[3]); \
    float eH0 = __expf(aH[0]), eH1 = __expf(aH[1]), eH2 = __expf(aH[2]), eH3 = __expf(aH[3]); \
    float s = eL0 + eL1 + eL2 + eL3 + eH0 + eH1 + eH2 + eH3; \
    s += __shfl_xor(s, 16); s += __shfl_xor(s, 32); \
    float rinv = 1.f / s; \
    ksm[H][lg * 4 + 0][nloc] = f2bf(eL0 * rinv); \
    ksm[H][lg * 4 + 1][nloc] = f2bf(eL1 * rinv); \
    ksm[H][lg * 4 + 2][nloc] = f2bf(eL2 * rinv); \
    ksm[H][lg * 4 + 3][nloc] = f2bf(eL3 * rinv); \
    ksm[H][16 + lg * 4 + 0][nloc] = f2bf(eH0 * rinv); \
    ksm[H][16 + lg * 4 + 1][nloc] = f2bf(eH1 * rinv); \
    ksm[H][16 + lg * 4 + 2][nloc] = f2bf(eH2 * rinv); \
    ksm[H][16 + lg * 4 + 3][nloc] = f2bf(eH3 * rinv); \
} while (0)

#define DO_V(J, HV, EB) do { \
    f32x4 acc = {0.f, 0.f, 0.f, 0.f}; \
    acc = MFMA16(wf[J][0], xb[0], acc); acc = MFMA16(wf[J][1], xb[1], acc); \
    acc = MFMA16(wf[J][2], xb[2], acc); acc = MFMA16(wf[J][3], xb[3], acc); \
    vls[HV][(EB) + lg * 4 + 0][nloc] = f2bf(acc[0]); \
    vls[HV][(EB) + lg * 4 + 1][nloc] = f2bf(acc[1]); \
    vls[HV][(EB) + lg * 4 + 2][nloc] = f2bf(acc[2]); \
    vls[HV][(EB) + lg * 4 + 3][nloc] = f2bf(acc[3]); \
} while (0)

__global__ __launch_bounds__(256, 2) void k_main(
    const float* __restrict__ x, const ushort* __restrict__ wbf,
    const float* __restrict__ scA, const float* __restrict__ biA,
    float* __restrict__ qsumP, float* __restrict__ ctxP) {
    int blk = blockIdx.x;
    int b = blk >> 6, nb = blk & 63;
    int tid = threadIdx.x, wid = tid >> 6, lane = tid & 63;
    int l15 = lane & 15, lg = lane >> 4;

    __shared__ __align__(16) ushort xs[4096];
    __shared__ __align__(16) ushort ksm[4][32][40];
    __shared__ __align__(16) ushort vls[4][32][40];

    bf16x8 wf[6][4];
    {
        const ushort* wr = wbf + (size_t)(wid * 96 + l15) * 128 + lg * 8;
        #pragma unroll
        for (int j = 0; j < 6; ++j)
            #pragma unroll
            for (int kc = 0; kc < 4; ++kc)
                wf[j][kc] = *(const bf16x8*)(wr + j * 2048 + kc * 32);
    }

    float qacc[6][4];
    #pragma unroll
    for (int j = 0; j < 6; ++j)
        #pragma unroll
        for (int r = 0; r < 4; ++r) qacc[j][r] = 0.f;
    f32x4 cacc[2][2];
    #pragma unroll
    for (int di = 0; di < 2; ++di)
        #pragma unroll
        for (int ei = 0; ei < 2; ++ei) cacc[di][ei] = (f32x4){0.f, 0.f, 0.f, 0.f};

    const int pk_ = tid & 7, pcb = tid >> 3;
    const float* xrow = x + (size_t)b * (C_ * N_) + nb * 256 + pk_ * 4;
    float scv[4], biv[4];
    #pragma unroll
    for (int i = 0; i < 4; ++i) {
        scv[i] = scA[b * 128 + pcb * 4 + i];
        biv[i] = biA[b * 128 + pcb * 4 + i];
    }
    unsigned boffj[4];
    #pragma unroll
    for (int j = 0; j < 4; ++j) {
        int n = pk_ * 4 + j;
        boffj[j] = (unsigned)(n * 256 + (((pcb >> 1) * 16) ^ ((n & 7) << 4)) + (pcb & 1) * 8);
    }

    float4 vbuf[4];
    #pragma unroll
    for (int i = 0; i < 4; ++i)
        vbuf[i] = *(const float4*)(xrow + (size_t)(pcb * 4 + i) * N_);

    for (int ch = 0; ch < 8; ++ch) {
        __syncthreads();
        unsigned e[4][4];
        #pragma unroll
        for (int i = 0; i < 4; ++i) {
            float s = scv[i], t = biv[i];
            e[i][0] = f2bf(vbuf[i].x * s + t);
            e[i][1] = f2bf(vbuf[i].y * s + t);
            e[i][2] = f2bf(vbuf[i].z * s + t);
            e[i][3] = f2bf(vbuf[i].w * s + t);
        }
        if (ch < 7) {
            #pragma unroll
            for (int i = 0; i < 4; ++i)
                vbuf[i] = *(const float4*)(xrow + (size_t)(pcb * 4 + i) * N_ + (ch + 1) * 32);
        }
        #pragma unroll
        for (int j = 0; j < 4; ++j) {
            u32x2 wj;
            wj.x = e[0][j] | (e[1][j] << 16);
            wj.y = e[2][j] | (e[3][j] << 16);
            *(u32x2*)((char*)xs + boffj[j]) = wj;
        }
        __syncthreads();

        #pragma unroll
        for (int nt = 0; nt < 2; ++nt) {
            int row = nt * 16 + l15;
            bf16x8 xb[4];
            #pragma unroll
            for (int kc = 0; kc < 4; ++kc) {
                unsigned off = (unsigned)(row * 256 +
                    (((kc * 4 + lg) * 16) ^ ((row & 7) << 4)));
                xb[kc] = *(const bf16x8*)((const char*)xs + off);
            }
            int nloc = nt * 16 + l15;

            if (wid == 0) {
                DO_Q(0); DO_Q(1); DO_Q(2); DO_Q(3); DO_Q(4); DO_Q(5);
            } else if (wid == 1) {
                DO_Q(0); DO_Q(1); DO_K(2, 0); DO_K(4, 1);
            } else if (wid == 2) {
                DO_K(0, 2); DO_K(2, 3); DO_V(4, 0, 0); DO_V(5, 0, 16);
            } else {
                DO_V(0, 1, 0); DO_V(1, 1, 16); DO_V(2, 2, 0);
                DO_V(3, 2, 16); DO_V(4, 3, 0); DO_V(5, 3, 16);
            }
        }
        __syncthreads();

        {
            bf16x8 A0 = *(const bf16x8*)&ksm[wid][l15][lg * 8];
            bf16x8 A1 = *(const bf16x8*)&ksm[wid][16 + l15][lg * 8];
            bf16x8 B0 = *(const bf16x8*)&vls[wid][l15][lg * 8];
            bf16x8 B1 = *(const bf16x8*)&vls[wid][16 + l15][lg * 8];
            cacc[0][0] = MFMA16(A0, B0, cacc[0][0]);
            cacc[0][1] = MFMA16(A0, B1, cacc[0][1]);
            cacc[1][0] = MFMA16(A1, B0, cacc[1][0]);
            cacc[1][1] = MFMA16(A1, B1, cacc[1][1]);
        }
    }

    int nq = (wid == 0) ? 6 : (wid == 1 ? 2 : 0);
    #pragma unroll
    for (int j = 0; j < 6; ++j) {
        if (j < nq) {
            #pragma unroll
            for (int r = 0; r < 4; ++r) {
                float s = qacc[j][r];
                s += __shfl_xor(s, 1); s += __shfl_xor(s, 2);
                s += __shfl_xor(s, 4); s += __shfl_xor(s, 8);
                if (l15 == 0)
                    qsumP[(size_t)blk * 128 + (wid * 6 + j) * 16 + lg * 4 + r] = s;
            }
        }
    }
    float* cp = ctxP + (size_t)blk * 4096 + wid * 1024;
    #pragma unroll
    for (int di = 0; di < 2; ++di)
        #pragma unroll
        for (int ei = 0; ei < 2; ++ei)
            #pragma unroll
            for (int r = 0; r < 4; ++r)
                cp[(di * 16 + lg * 4 + r) * 32 + ei * 16 + l15] = cacc[di][ei][r];
}

// ---------------- K2.5: reduce ctxP over the 64 n-blocks (into q=0 slice) ----
__global__ void k_red(float* __restrict__ ctxP) {
    int blk = blockIdx.x;  // B*8
    int b = blk >> 3, sl = blk & 7;
    float* base = ctxP + (size_t)b * 64 * 4096;
    #pragma unroll
    for (int r = 0; r < 2; ++r) {
        int i = sl * 512 + r * 256 + threadIdx.x;
        float s = 0.f;
        for (int q = 0; q < 64; ++q) s += base[(size_t)q * 4096 + i];
        base[i] = s;
    }
}

// ---------------- K3: combine partials, build M''[b][c][hd] bf16 ----------------
__global__ void k_comb(const float* __restrict__ ctxP, const float* __restrict__ qsumP,
                       const float* __restrict__ projw, ushort* __restrict__ mpp) {
    int b = blockIdx.x, tid = threadIdx.x;
    __shared__ float ctx[4096];
    __shared__ float qinv[128];
    for (int i = tid; i < 4096; i += 256)
        ctx[i] = ctxP[(size_t)b * 64 * 4096 + i];
    if (tid < 128) {
        float s = 0.f;
        const float* p = qsumP + (size_t)b * 64 * 128 + tid;
        for (int q = 0; q < 64; ++q) s += p[q * 128];
        qinv[tid] = 1.f / s;
    }
    __syncthreads();
    int c = tid >> 1, hd0 = (tid & 1) * 64;
    unsigned ow[32];
    for (int k = 0; k < 64; ++k) {
        int hd = hd0 + k, h = hd >> 5, d = hd & 31;
        const float* pw = projw + c * 128 + h * 32;
        const float* cx = ctx + h * 1024 + d * 32;
        float s = 0.f;
        #pragma unroll 8
        for (int e = 0; e < 32; ++e) s += pw[e] * cx[e];
        s *= qinv[hd];
        ushort bv = f2bf(s);
        if (k & 1) ow[k >> 1] |= ((unsigned)bv) << 16; else ow[k >> 1] = bv;
    }
    ushort* dst = mpp + ((size_t)(b * 128 + c)) * 128 + hd0;
    #pragma unroll
    for (int q = 0; q < 8; ++q) {
        uint4 t; t.x = ow[q * 4]; t.y = ow[q * 4 + 1]; t.z = ow[q * 4 + 2]; t.w = ow[q * 4 + 3];
        ((uint4*)dst)[q] = t;
    }
}

// ---------------- K4: recompute eq, out = eq . M''^T + proj_b + x ----------------
// 64n x 128c per block, grid 4096. x loaded ONCE (Phase A), kept in xv[8]
// registers for the Phase-D residual. att rows padded to 136B (R15 change).
#define ATT_STRIDE 136
__global__ __launch_bounds__(256) void k_final(
    const ushort* __restrict__ wbf, const ushort* __restrict__ mpp,
    const float* __restrict__ scA, const float* __restrict__ biA,
    const float* __restrict__ projb, const float* __restrict__ x,
    float* __restrict__ out) {
    int blk = blockIdx.x;
    int b = blk >> 8, nb = blk & 255;
    int tid = threadIdx.x, wid = tid >> 6, lane = tid & 63;
    int l15 = lane & 15, lg = lane >> 4;
    int n0 = nb * 64;

    __shared__ __align__(16) char lds[33792];
    ushort* xs   = (ushort*)lds;            // 16 KB, dead after Phase B
    char*   att  = lds;                     // 128 x 136B = 17408 B, aliases xs
    ushort* eqls = (ushort*)(lds + 17408);  // 16 KB

    bf16x8 wq[2][4];
    #pragma unroll
    for (int j = 0; j < 2; ++j) {
        const ushort* wr = wbf + (size_t)((wid * 2 + j) * 16 + l15) * 128 + lg * 8;
        #pragma unroll
        for (int kc = 0; kc < 4; ++kc) wq[j][kc] = *(const bf16x8*)(wr + kc * 32);
    }
    bf16x8 bm[2][4];
    #pragma unroll
    for (int ctk = 0; ctk < 2; ++ctk) {
        const ushort* br = mpp + ((size_t)(b * 128 + (wid * 2 + ctk) * 16 + l15)) * 128 + lg * 8;
        #pragma unroll
        for (int kc = 0; kc < 4; ++kc) bm[ctk][kc] = *(const bf16x8*)(br + kc * 32);
    }

    // ---- Phase A: x -> xs (swizzled); raw x retained in xv[8]
    const int pk_ = tid & 15, pcb = tid >> 4;
    float4 xv[8];
    {
        const float* xrow = x + (size_t)b * (C_ * N_) + n0 + pk_ * 4;
        unsigned e[8][4];
        #pragma unroll
        for (int i = 0; i < 8; ++i) {
            int c = pcb * 8 + i;
            float s = scA[b * 128 + c], t = biA[b * 128 + c];
            xv[i] = *(const float4*)(xrow + (size_t)c * N_);
            e[i][0] = f2bf(xv[i].x * s + t);
            e[i][1] = f2bf(xv[i].y * s + t);
            e[i][2] = f2bf(xv[i].z * s + t);
            e[i][3] = f2bf(xv[i].w * s + t);
        }
        #pragma unroll
        for (int j = 0; j < 4; ++j) {
            int n = pk_ * 4 + j;
            uint4 wj;
            wj.x = e[0][j] | (e[1][j] << 16);
            wj.y = e[2][j] | (e[3][j] << 16);
            wj.z = e[4][j] | (e[5][j] << 16);
            wj.w = e[6][j] | (e[7][j] << 16);
            unsigned byte = (unsigned)(n * 256 + ((pcb * 16) ^ ((n & 7) << 4)));
            *(uint4*)((char*)xs + byte) = wj;
        }
    }
    __syncthreads();

    // ---- Phase B: q-MFMA + exp -> eqls[n][hd] (swizzled)
    #pragma unroll
    for (int nt = 0; nt < 4; ++nt) {
        int row = nt * 16 + l15;
        bf16x8 xb[4];
        #pragma unroll
        for (int kc = 0; kc < 4; ++kc) {
            unsigned off = (unsigned)(row * 256 + (((kc * 4 + lg) * 16) ^ ((row & 7) << 4)));
            xb[kc] = *(const bf16x8*)((const char*)xs + off);
        }
        #pragma unroll
        for (int j = 0; j < 2; ++j) {
            f32x4 a = {0.f, 0.f, 0.f, 0.f};
            #pragma unroll
            for (int kc = 0; kc < 4; ++kc) a = MFMA16(wq[j][kc], xb[kc], a);
            u32x2 pk;
            pk.x = (unsigned)f2bf(__expf(a[0])) | ((unsigned)f2bf(__expf(a[1])) << 16);
            pk.y = (unsigned)f2bf(__expf(a[2])) | ((unsigned)f2bf(__expf(a[3])) << 16);
            int ot = wid * 2 + j;
            unsigned byte = (unsigned)(row * 256 +
                (((ot * 2 + (lg >> 1)) * 16) ^ ((row & 7) << 4)) + (lg & 1) * 8);
            *(u32x2*)((char*)eqls + byte) = pk;
        }
    }
    __syncthreads();  // eqls visible; xs dead -> att may overwrite

    // ---- Phase C: out-MFMA (A=eqls, B=mpp) -> att[c][n] (136B rows, (c&7) swizzle)
    #pragma unroll
    for (int nt = 0; nt < 4; ++nt) {
        int row = nt * 16 + l15;
        bf16x8 af[4];
        #pragma unroll
        for (int kc = 0; kc < 4; ++kc) {
            unsigned off = (unsigned)(row * 256 + (((kc * 4 + lg) * 16) ^ ((row & 7) << 4)));
            af[kc] = *(const bf16x8*)((const char*)eqls + off);
        }
        #pragma unroll
        for (int ctk = 0; ctk < 2; ++ctk) {
            f32x4 a = {0.f, 0.f, 0.f, 0.f};
            #pragma unroll
            for (int kc = 0; kc < 4; ++kc) a = MFMA16(af[kc], bm[ctk][kc], a);
            int c = (wid * 2 + ctk) * 16 + l15;  // D: col=c, row=n
            u32x2 pk;
            pk.x = (unsigned)f2bf(a[0]) | ((unsigned)f2bf(a[1]) << 16);
            pk.y = (unsigned)f2bf(a[2]) | ((unsigned)f2bf(a[3]) << 16);
            unsigned byte = (unsigned)(c * ATT_STRIDE +
                (((nt * 2 + (lg >> 1)) * 16) ^ ((c & 7) << 4)) + (lg & 1) * 8);
            *(u32x2*)(att + byte) = pk;
        }
    }
    __syncthreads();

    // ---- Phase D: readback + register residual + coalesced store
    {
        size_t obase = (size_t)b * (C_ * N_) + n0 + pk_ * 4;
        #pragma unroll
        for (int i = 0; i < 8; ++i) {
            int c = pcb * 8 + i;
            unsigned byte = (unsigned)(c * ATT_STRIDE +
                (((pk_ >> 1) * 16) ^ ((c & 7) << 4)) + (pk_ & 1) * 8);
            u32x2 pk = *(const u32x2*)(att + byte);
            float pbv = projb[c];
            f32x4 o4;
            o4[0] = bf2f(pk.x & 0xffffu) + pbv + xv[i].x;
            o4[1] = bf2f(pk.x >> 16)     + pbv + xv[i].y;
            o4[2] = bf2f(pk.y & 0xffffu) + pbv + xv[i].z;
            o4[3] = bf2f(pk.y >> 16)     + pbv + xv[i].w;
            *(f32x4*)(out + obase + (size_t)c * N_) = o4;
        }
    }
}

extern "C" void kernel_launch(void* const* d_in, const int* in_sizes, int n_in,
                              void* d_out, int out_size, void* d_ws, size_t ws_size,
                              hipStream_t stream) {
    const float* x     = (const float*)d_in[0];
    const float* gnw   = (const float*)d_in[1];
    const float* gnb   = (const float*)d_in[2];
    const float* qkvw  = (const float*)d_in[3];
    const float* projw = (const float*)d_in[4];
    const float* projb = (const float*)d_in[5];
    float* out = (float*)d_out;

    char* ws = (char*)d_ws;
    ushort* wbf   = (ushort*)(ws);                // 98,304 B
    float*  qsumP = (float*)(ws + 102400);        // 524,288 B
    ushort* mpp   = (ushort*)(ws + 626688);       // 524,288 B
    float*  sc    = (float*)(ws + 1150976);       // 8,192 B
    float*  bi    = (float*)(ws + 1159168);       // 8,192 B
    float*  ctxP  = (float*)(ws + 1167360);       // 16,777,216 B (end: 17,944,576)

    k_stats<<<560,  1024, 0, stream>>>(x, gnw, gnb, sc, bi, qkvw, wbf);
    k_main <<<1024, 256,  0, stream>>>(x, wbf, sc, bi, qsumP, ctxP);
    k_red  <<<128,  256,  0, stream>>>(ctxP);
    k_comb <<<16,   256,  0, stream>>>(ctxP, qsumP, projw, mpp);
    k_final<<<4096, 256,  0, stream>>>(wbf, mpp, sc, bi, projb, x, out);
}